// Round 1
// baseline (146.437 us; speedup 1.0000x reference)
//
#include <hip/hip_runtime.h>

#define SK 8192
#define SQ 8192
#define DD 128
#define ZSPLIT 8

typedef __attribute__((ext_vector_type(8))) short short8;
typedef __attribute__((ext_vector_type(4))) float f32x4;
typedef unsigned short ushort_t;

// round-to-nearest-even f32 -> bf16
__device__ __forceinline__ unsigned short f2bf(float x){
  unsigned int u = __float_as_uint(x);
  u += 0x7FFFu + ((u >> 16) & 1u);
  return (unsigned short)(u >> 16);
}

// ---------------------------------------------------------------------------
// prep_kq: cast K (pre-scaled by log2(e)/sqrt(128)) and Q to bf16, stored as
// pre-swizzled 64-row tile images (row stride 256B, 16B-slot XOR swizzle)
// so kernels can stage tiles with plain linear 16B copies and read MFMA
// fragments with conflict-free ds_read_b128.
// element (row r in tile, d): byte = r*256 + (((d>>3)*16) ^ ((r&7)<<4)) + (d&7)*2
// ---------------------------------------------------------------------------
__global__ __launch_bounds__(256) void prep_kq(const float* __restrict__ Kp,
                                               const float* __restrict__ Qp,
                                               ushort_t* __restrict__ kws,
                                               ushort_t* __restrict__ qws){
  int g = blockIdx.x*256 + threadIdx.x;      // 0..262143 (2 arrays x 8192 rows x 16 slots)
  int arr = g >> 17;
  int s   = g & 131071;
  int row = s >> 4;
  int c16 = s & 15;
  const float* src = (arr ? Qp : Kp) + row*DD + c16*8;
  const float scale = arr ? 1.0f : 0.12751743f;   // log2(e)/sqrt(128)
  float4 f0 = ((const float4*)src)[0];
  float4 f1 = ((const float4*)src)[1];
  unsigned int wv[4];
  wv[0] = (unsigned)f2bf(f0.x*scale) | ((unsigned)f2bf(f0.y*scale) << 16);
  wv[1] = (unsigned)f2bf(f0.z*scale) | ((unsigned)f2bf(f0.w*scale) << 16);
  wv[2] = (unsigned)f2bf(f1.x*scale) | ((unsigned)f2bf(f1.y*scale) << 16);
  wv[3] = (unsigned)f2bf(f1.z*scale) | ((unsigned)f2bf(f1.w*scale) << 16);
  ushort_t* base = arr ? qws : kws;
  int tile = row >> 6, r = row & 63;
  char* dst = (char*)(base + (size_t)tile*8192) + r*256 + ((c16*16) ^ ((r&7)<<4));
  ((uint4*)dst)[0] = make_uint4(wv[0],wv[1],wv[2],wv[3]);
}

// ---------------------------------------------------------------------------
// prep_v: V [8192 q][128 dv] fp32 -> V^T tile images: per 64-q tile, a
// [128 dv][64 q] bf16 image, row stride 128B, 16B-slot XOR swizzle:
// element (dv, q): byte = dv*128 + ((((q&63)>>3)*16) ^ ((dv&7)<<4)) + (q&7)*2
// ---------------------------------------------------------------------------
__global__ __launch_bounds__(256) void prep_v(const float* __restrict__ Vp,
                                              ushort_t* __restrict__ vtws){
  __shared__ ushort_t vl[64][132];
  int tile = blockIdx.x;    // 0..127
  int t = threadIdx.x;
  int q = t >> 2, dvb = (t & 3)*32;
  const float* src = Vp + (size_t)(tile*64 + q)*DD + dvb;
  #pragma unroll
  for (int j=0;j<8;j++){
    float4 f = ((const float4*)src)[j];
    vl[q][dvb + j*4 + 0] = f2bf(f.x);
    vl[q][dvb + j*4 + 1] = f2bf(f.y);
    vl[q][dvb + j*4 + 2] = f2bf(f.z);
    vl[q][dvb + j*4 + 3] = f2bf(f.w);
  }
  __syncthreads();
  char* obase = (char*)(vtws + (size_t)tile*8192);
  #pragma unroll
  for (int s2=0;s2<4;s2++){
    int sid = t*4 + s2;           // 0..1023 = 128 dv x 8 q-slots
    int dv = sid >> 3, qs = sid & 7;
    unsigned int wv[4];
    #pragma unroll
    for (int p=0;p<4;p++){
      unsigned lo = vl[qs*8 + p*2 + 0][dv];
      unsigned hi = vl[qs*8 + p*2 + 1][dv];
      wv[p] = lo | (hi << 16);
    }
    char* dst = obase + dv*128 + ((qs*16) ^ ((dv&7)<<4));
    ((uint4*)dst)[0] = make_uint4(wv[0],wv[1],wv[2],wv[3]);
  }
}

// ---------------------------------------------------------------------------
// kz: per-column stats. WG = (q-stripe of 64) x (k-split of 8192/8).
// zpart[ks][q] = sum over that k range of 2^a,  a = (K*log2e/sqrt(d)) . Q
// ---------------------------------------------------------------------------
__global__ __launch_bounds__(256) void kz(const ushort_t* __restrict__ kws,
                                          const ushort_t* __restrict__ qws,
                                          float* __restrict__ zpart){
  __shared__ ushort_t Qs[8192];   // 16KB: q-stripe image (64 rows x 128 d)
  __shared__ ushort_t Ks[8192];   // 16KB: current K tile image
  int wg = blockIdx.x;            // 1024
  int qs   = wg >> 3;             // 0..127
  int kspl = wg & 7;
  int t = threadIdx.x, lane = t & 63, w = t >> 6;
  int r15 = lane & 15, g4 = lane >> 4;
  { const uint4* srcq = (const uint4*)(qws + (size_t)qs*8192);
    uint4* d = (uint4*)Qs;
    for (int i=t;i<1024;i+=256) d[i] = srcq[i]; }
  float zacc = 0.f;
  for (int it=0; it<(SK/64)/ZSPLIT; ++it){
    int kt = kspl*((SK/64)/ZSPLIT) + it;
    __syncthreads();
    { const uint4* srck = (const uint4*)(kws + (size_t)kt*8192);
      uint4* d = (uint4*)Ks;
      for (int i=t;i<1024;i+=256) d[i] = srck[i]; }
    __syncthreads();
    #pragma unroll
    for (int mf=0; mf<4; ++mf){
      f32x4 s = {0.f,0.f,0.f,0.f};
      #pragma unroll
      for (int kk=0; kk<4; ++kk){
        int arow = mf*16 + r15;
        short8 a = *(const short8*)((const char*)Ks + arow*256 + ((kk*64 + g4*16) ^ ((arow&7)<<4)));
        int brow = w*16 + r15;
        short8 b = *(const short8*)((const char*)Qs + brow*256 + ((kk*64 + g4*16) ^ ((brow&7)<<4)));
        s = __builtin_amdgcn_mfma_f32_16x16x32_bf16(a, b, s, 0, 0, 0);
      }
      zacc += __builtin_exp2f(s[0]) + __builtin_exp2f(s[1])
            + __builtin_exp2f(s[2]) + __builtin_exp2f(s[3]);
    }
  }
  zacc += __shfl_xor(zacc, 16);
  zacc += __shfl_xor(zacc, 32);
  if (lane < 16)
    zpart[(size_t)kspl*SQ + qs*64 + w*16 + lane] = zacc;
}

// c_q = log2( sum of partials )
__global__ __launch_bounds__(256) void kc(const float* __restrict__ zpart,
                                          float* __restrict__ carr){
  int q = blockIdx.x*256 + threadIdx.x;
  float z = 0.f;
  #pragma unroll
  for (int s=0;s<ZSPLIT;s++) z += zpart[(size_t)s*SQ + q];
  carr[q] = __builtin_log2f(z);
}

// ---------------------------------------------------------------------------
// ko: main fused pass. WG = (k-tile of 128 rows) x (q-split of 2048).
// Per 64-q iteration: S = K~ . Q~^T (MFMA), P = 2^(S - c_q) -> bf16 LDS,
// O += P . V (MFMA).  Epilogue: atomicAdd into zeroed d_out.
// 8 waves: wave (wm = w>>2, wn = w&3). G1: wave tile = 64 rows x 16 q.
// G2: wave tile = 64 rows x 32 dv.
// ---------------------------------------------------------------------------
__global__ __launch_bounds__(512) void ko(const ushort_t* __restrict__ kws,
                                          const ushort_t* __restrict__ qws,
                                          const ushort_t* __restrict__ vtws,
                                          const float* __restrict__ carr,
                                          float* __restrict__ out){
  __shared__ ushort_t Ks[16384];  // 32KB: two 64-row K tile images
  __shared__ ushort_t Qs[8192];   // 16KB
  __shared__ ushort_t Vs[8192];   // 16KB (V^T tile image [128 dv][64 q])
  __shared__ ushort_t Ps[8192];   // 16KB ([128 k][64 q] bf16, swizzled)
  int wg = blockIdx.x;            // 256
  int ktile = wg >> 2;            // 0..63
  int qsp   = wg & 3;
  int t = threadIdx.x, lane = t & 63, w = t >> 6;
  int wm = w >> 2, wn = w & 3;
  int r15 = lane & 15, g4 = lane >> 4;
  { const uint4* src = (const uint4*)(kws + (size_t)ktile*16384);
    uint4* d = (uint4*)Ks;
    for (int i=t;i<2048;i+=512) d[i] = src[i]; }
  f32x4 zero = {0.f,0.f,0.f,0.f};
  f32x4 acc[4][2];
  #pragma unroll
  for (int i=0;i<4;i++){ acc[i][0]=zero; acc[i][1]=zero; }

  for (int it=0; it<32; ++it){
    int qt = qsp*32 + it;         // q-tile index, q0 = qt*64
    __syncthreads();
    { const uint4* sq = (const uint4*)(qws + (size_t)qt*8192);
      const uint4* sv = (const uint4*)(vtws + (size_t)qt*8192);
      uint4* dq = (uint4*)Qs; uint4* dv_ = (uint4*)Vs;
      for (int i=t;i<1024;i+=512){ dq[i]=sq[i]; dv_[i]=sv[i]; } }
    __syncthreads();
    float c_lane = carr[qt*64 + wn*16 + r15];
    // ---- G1: scores + exp2 -> Ps ----
    #pragma unroll
    for (int mf=0; mf<4; ++mf){
      f32x4 s = {0.f,0.f,0.f,0.f};
      #pragma unroll
      for (int kk=0; kk<4; ++kk){
        int arow = wm*64 + mf*16 + r15;
        const char* kbase = (const char*)Ks + (arow>>6)*16384;
        int ar = arow & 63;
        short8 a = *(const short8*)(kbase + ar*256 + ((kk*64 + g4*16) ^ ((ar&7)<<4)));
        int brow = wn*16 + r15;
        short8 b = *(const short8*)((const char*)Qs + brow*256 + ((kk*64 + g4*16) ^ ((brow&7)<<4)));
        s = __builtin_amdgcn_mfma_f32_16x16x32_bf16(a, b, s, 0, 0, 0);
      }
      #pragma unroll
      for (int j=0;j<4;j++){
        float p = __builtin_exp2f(s[j] - c_lane);
        int prow = wm*64 + mf*16 + g4*4 + j;      // C layout: row=(lane>>4)*4+j
        int pcolb = (wn*16 + r15)*2;              // col = lane&15
        *(ushort_t*)((char*)Ps + prow*128 + ((pcolb & ~15) ^ ((prow&7)<<4)) + (pcolb & 15)) = f2bf(p);
      }
    }
    __syncthreads();
    // ---- G2: O += P . V ----
    #pragma unroll
    for (int kk=0; kk<2; ++kk){
      int dv0 = wn*32 + r15;
      short8 b0 = *(const short8*)((const char*)Vs + dv0*128 + (((kk*4+g4)*16) ^ ((dv0&7)<<4)));
      int dv1 = wn*32 + 16 + r15;
      short8 b1 = *(const short8*)((const char*)Vs + dv1*128 + (((kk*4+g4)*16) ^ ((dv1&7)<<4)));
      #pragma unroll
      for (int mf=0; mf<4; ++mf){
        int prow = wm*64 + mf*16 + r15;
        short8 a = *(const short8*)((const char*)Ps + prow*128 + (((kk*4+g4)*16) ^ ((prow&7)<<4)));
        acc[mf][0] = __builtin_amdgcn_mfma_f32_16x16x32_bf16(a, b0, acc[mf][0], 0, 0, 0);
        acc[mf][1] = __builtin_amdgcn_mfma_f32_16x16x32_bf16(a, b1, acc[mf][1], 0, 0, 0);
      }
    }
  }
  // ---- epilogue: accumulate across the 4 q-split WGs ----
  #pragma unroll
  for (int mf=0; mf<4; ++mf)
    #pragma unroll
    for (int nf=0; nf<2; ++nf)
      #pragma unroll
      for (int j=0;j<4;j++){
        int k  = ktile*128 + wm*64 + mf*16 + g4*4 + j;
        int dv = wn*32 + nf*16 + r15;
        atomicAdd(out + (size_t)k*DD + dv, acc[mf][nf][j]);
      }
}

extern "C" void kernel_launch(void* const* d_in, const int* in_sizes, int n_in,
                              void* d_out, int out_size, void* d_ws, size_t ws_size,
                              hipStream_t stream) {
  const float* Kp = (const float*)d_in[0];
  const float* Qp = (const float*)d_in[1];
  const float* Vp = (const float*)d_in[2];
  float* out = (float*)d_out;
  char* ws = (char*)d_ws;
  // ws layout: K~ 2MB | Q~ 2MB | V^T 2MB | zpart 256KB | c 32KB  (~6.3MB)
  ushort_t* kws  = (ushort_t*)ws;
  ushort_t* qws  = (ushort_t*)(ws + ((size_t)2<<20));
  ushort_t* vtws = (ushort_t*)(ws + ((size_t)4<<20));
  float* zpart   = (float*)(ws + ((size_t)6<<20));
  float* carr    = (float*)(ws + ((size_t)6<<20) + ((size_t)256<<10));

  hipMemsetAsync(d_out, 0, (size_t)SK*DD*sizeof(float), stream);
  prep_kq<<<dim3(1024), dim3(256), 0, stream>>>(Kp, Qp, kws, qws);
  prep_v <<<dim3(128),  dim3(256), 0, stream>>>(Vp, vtws);
  kz     <<<dim3(1024), dim3(256), 0, stream>>>(kws, qws, zpart);
  kc     <<<dim3(SQ/256), dim3(256), 0, stream>>>(zpart, carr);
  ko     <<<dim3(256),  dim3(512), 0, stream>>>(kws, qws, vtws, carr, out);
}